// Round 1
// baseline (1539.167 us; speedup 1.0000x reference)
//
#include <hip/hip_runtime.h>

#define HID 256
#define FANOUT 10
#define BM 64
#define BK 16

// ---------------------------------------------------------------------------
// agg[t,:] = mean over 10 neighbors of x[src[10t+j], :]
// One wave (64 lanes) per target; lane reads one float4 (4 cols) per neighbor.
// ---------------------------------------------------------------------------
__global__ __launch_bounds__(256)
void agg_kernel(const float* __restrict__ x, const int* __restrict__ src,
                float* __restrict__ agg, int T) {
    const int wave = threadIdx.x >> 6;
    const int lane = threadIdx.x & 63;
    const int t = blockIdx.x * 4 + wave;
    if (t >= T) return;
    const float4* x4 = (const float4*)x;
    const int* sp = src + (size_t)t * FANOUT;
    float sx = 0.f, sy = 0.f, sz = 0.f, sw = 0.f;
#pragma unroll
    for (int j = 0; j < FANOUT; ++j) {
        const int s = sp[j];
        const float4 v = x4[(size_t)s * 64 + lane];
        sx += v.x; sy += v.y; sz += v.z; sw += v.w;
    }
    float4 o;
    o.x = sx * 0.1f; o.y = sy * 0.1f; o.z = sz * 0.1f; o.w = sw * 0.1f;
    ((float4*)agg)[(size_t)t * 64 + lane] = o;
}

// ---------------------------------------------------------------------------
// h = agg@Wl + x[tlid]@Wr + bias, written IN PLACE over agg.
// Block computes a full-width [64 x 256] tile (so in-place is safe: each row
// is read only by its own block, writes happen after the K loop).
// K = 512: first 256 from agg/Wl, second 256 from gathered x[tlid]/Wr.
// 256 threads: ty=tid/16 -> 4 rows, tx=tid%16 -> 16 cols; 4x16 accs/thread.
// ---------------------------------------------------------------------------
__global__ __launch_bounds__(256)
void sage_gemm_kernel(float* __restrict__ hbuf, const float* __restrict__ x,
                      const int* __restrict__ tlid,
                      const float* __restrict__ Wl, const float* __restrict__ Wr,
                      const float* __restrict__ bias, int T) {
    __shared__ float w_lds[BK][HID];      // 16 KB
    __shared__ float a_lds[BK][BM + 4];   // padded stride 68 (17 float4s)
    const int tid = threadIdx.x;
    const int tx = tid & 15, ty = tid >> 4;
    const int r0 = blockIdx.x * BM;
    const int ar = tid >> 2;              // 0..63 : row this thread stages
    const int ac = (tid & 3) << 2;        // 0,4,8,12 : col group

    float acc[4][16];
#pragma unroll
    for (int i = 0; i < 4; ++i)
#pragma unroll
        for (int j = 0; j < 16; ++j) acc[i][j] = 0.f;

    const size_t arow = (size_t)(r0 + ar) * HID;
    const size_t xrow = (size_t)tlid[r0 + ar] * HID;

    for (int chunk = 0; chunk < 32; ++chunk) {
        const int k0 = chunk * BK;
        const bool second = (k0 >= HID);
        const int kk = second ? (k0 - HID) : k0;

        // stage W chunk [16 x 256] (row-major, float4-coalesced)
        const float4* Wsrc = (const float4*)((second ? Wr : Wl) + (size_t)kk * HID);
        float4* wd = (float4*)&w_lds[0][0];
#pragma unroll
        for (int i = 0; i < 4; ++i)
            wd[tid + i * 256] = Wsrc[tid + i * 256];

        // stage A chunk [64 rows x 16 cols], transposed into a_lds[k][row]
        const float* asrc = second ? (x + xrow) : (hbuf + arow);
        const float4 av = *(const float4*)(asrc + kk + ac);
        a_lds[ac + 0][ar] = av.x;
        a_lds[ac + 1][ar] = av.y;
        a_lds[ac + 2][ar] = av.z;
        a_lds[ac + 3][ar] = av.w;
        __syncthreads();

#pragma unroll
        for (int k = 0; k < BK; ++k) {
            const float4 a4 = *(const float4*)&a_lds[k][ty << 2];
            const float aa[4] = {a4.x, a4.y, a4.z, a4.w};
#pragma unroll
            for (int j = 0; j < 4; ++j) {
                const float4 b4 = *(const float4*)&w_lds[k][(tx << 4) + (j << 2)];
#pragma unroll
                for (int i = 0; i < 4; ++i) {
                    acc[i][j * 4 + 0] = fmaf(aa[i], b4.x, acc[i][j * 4 + 0]);
                    acc[i][j * 4 + 1] = fmaf(aa[i], b4.y, acc[i][j * 4 + 1]);
                    acc[i][j * 4 + 2] = fmaf(aa[i], b4.z, acc[i][j * 4 + 2]);
                    acc[i][j * 4 + 3] = fmaf(aa[i], b4.w, acc[i][j * 4 + 3]);
                }
            }
        }
        __syncthreads();
    }

    // epilogue: + bias, store in place
#pragma unroll
    for (int j = 0; j < 4; ++j) {
        const float4 bv = *(const float4*)&bias[(tx << 4) + (j << 2)];
#pragma unroll
        for (int i = 0; i < 4; ++i) {
            acc[i][j * 4 + 0] += bv.x;
            acc[i][j * 4 + 1] += bv.y;
            acc[i][j * 4 + 2] += bv.z;
            acc[i][j * 4 + 3] += bv.w;
        }
    }
#pragma unroll
    for (int i = 0; i < 4; ++i) {
        float* orow = hbuf + (size_t)(r0 + (ty << 2) + i) * HID + (tx << 4);
#pragma unroll
        for (int j = 0; j < 4; ++j) {
            const float4 o = make_float4(acc[i][j * 4 + 0], acc[i][j * 4 + 1],
                                         acc[i][j * 4 + 2], acc[i][j * 4 + 3]);
            *(float4*)(orow + (j << 2)) = o;
        }
    }
}

// ---------------------------------------------------------------------------
__global__ void zero_kernel(float* p) { p[threadIdx.x] = 0.f; }  // 512 threads

__global__ __launch_bounds__(256)
void stats_kernel(const float* __restrict__ h, float* __restrict__ ssum,
                  float* __restrict__ ssq, int T) {
    const int c = threadIdx.x;  // 256 columns
    float s = 0.f, q = 0.f;
    for (int r = blockIdx.x; r < T; r += gridDim.x) {
        const float v = h[(size_t)r * HID + c];
        s += v;
        q += v * v;
    }
    atomicAdd(&ssum[c], s);
    atomicAdd(&ssq[c], q);
}

__global__ void bnfin_kernel(const float* __restrict__ ssum, const float* __restrict__ ssq,
                             const float* __restrict__ g, const float* __restrict__ be,
                             float* __restrict__ scal, float* __restrict__ shft,
                             float invT) {
    const int c = threadIdx.x;
    const float mu = ssum[c] * invT;
    float var = ssq[c] * invT - mu * mu;
    var = fmaxf(var, 0.f);
    const float rs = rsqrtf(var + 1e-5f);
    const float sc = rs * g[c];
    scal[c] = sc;
    shft[c] = be[c] - mu * sc;
}

__global__ __launch_bounds__(256)
void norm_kernel(float* __restrict__ h, const float* __restrict__ scal,
                 const float* __restrict__ shft, int n4) {
    const int i = blockIdx.x * blockDim.x + threadIdx.x;
    if (i >= n4) return;
    const int c4 = i & 63;
    float4 v = ((float4*)h)[i];
    const float4 sc = ((const float4*)scal)[c4];
    const float4 sh = ((const float4*)shft)[c4];
    v.x = fmaxf(fmaf(v.x, sc.x, sh.x), 0.f);
    v.y = fmaxf(fmaf(v.y, sc.y, sh.y), 0.f);
    v.z = fmaxf(fmaf(v.z, sc.z, sh.z), 0.f);
    v.w = fmaxf(fmaf(v.w, sc.w, sh.w), 0.f);
    ((float4*)h)[i] = v;
}

// ---------------------------------------------------------------------------
// out[r, n] = x3[r,:] . fc_w[:, n] + fc_b[n]   (512 x 47)
// ---------------------------------------------------------------------------
__global__ __launch_bounds__(64)
void fc_kernel(const float* __restrict__ x, const float* __restrict__ w,
               const float* __restrict__ b, float* __restrict__ out, int C) {
    __shared__ float row[HID];
    const int r = blockIdx.x;
    const int tid = threadIdx.x;
    ((float4*)row)[tid] = ((const float4*)(x + (size_t)r * HID))[tid];
    __syncthreads();
    if (tid < C) {
        float acc = b[tid];
#pragma unroll 8
        for (int k = 0; k < HID; ++k)
            acc = fmaf(row[k], w[k * C + tid], acc);
        out[(size_t)r * C + tid] = acc;
    }
}

// ---------------------------------------------------------------------------
extern "C" void kernel_launch(void* const* d_in, const int* in_sizes, int n_in,
                              void* d_out, int out_size, void* d_ws, size_t ws_size,
                              hipStream_t stream) {
    // dict order: x_feat, then per layer i: src,dst,tlid,Wl,Wr,b,g,be; fc_w, fc_b
    const float* x_feat = (const float*)d_in[0];
    const int T0 = in_sizes[3];   // tlid0 count = 61952
    const int T1 = in_sizes[11];  // 5632
    const int T2 = in_sizes[19];  // 512
    const int NCLS = in_sizes[26];

    float* buf0 = (float*)d_ws;                  // [T0,256] agg->h->x1 in place
    float* buf1 = buf0 + (size_t)T0 * HID;       // [T1,256]
    float* buf2 = buf1 + (size_t)T1 * HID;       // [T2,256]
    float* ssum = buf2 + (size_t)T2 * HID;       // [256]
    float* ssq  = ssum + HID;                    // [256]
    float* scal = ssq + HID;                     // [256]
    float* shft = scal + HID;                    // [256]

    const float* xs[3]  = { x_feat, buf0, buf1 };
    float*       bufs[3] = { buf0, buf1, buf2 };
    const int    Ts[3]  = { T0, T1, T2 };

    for (int i = 0; i < 3; ++i) {
        const int base = 1 + i * 8;
        const int*   src  = (const int*)d_in[base + 0];
        const int*   tlid = (const int*)d_in[base + 2];
        const float* Wl   = (const float*)d_in[base + 3];
        const float* Wr   = (const float*)d_in[base + 4];
        const float* bi   = (const float*)d_in[base + 5];
        const float* g    = (const float*)d_in[base + 6];
        const float* be   = (const float*)d_in[base + 7];
        const int T = Ts[i];

        agg_kernel<<<(T + 3) / 4, 256, 0, stream>>>(xs[i], src, bufs[i], T);
        zero_kernel<<<1, 512, 0, stream>>>(ssum);  // zeros ssum+ssq (contiguous)
        sage_gemm_kernel<<<T / BM, 256, 0, stream>>>(bufs[i], xs[i], tlid, Wl, Wr, bi, T);
        int sg = T / 64;
        if (sg > 256) sg = 256;
        if (sg < 1) sg = 1;
        stats_kernel<<<sg, 256, 0, stream>>>(bufs[i], ssum, ssq, T);
        bnfin_kernel<<<1, HID, 0, stream>>>(ssum, ssq, g, be, scal, shft, 1.0f / (float)T);
        norm_kernel<<<(T * 64 + 255) / 256, 256, 0, stream>>>(bufs[i], scal, shft, T * 64);
    }

    const float* fc_w = (const float*)d_in[25];
    const float* fc_b = (const float*)d_in[26];
    fc_kernel<<<T2, 64, 0, stream>>>(buf2, fc_w, fc_b, (float*)d_out, NCLS);
}

// Round 2
// 1152.372 us; speedup vs baseline: 1.3357x; 1.3357x over previous
//
#include <hip/hip_runtime.h>

#define HID 256
#define FANOUT 10

typedef __attribute__((ext_vector_type(8))) short bf16x8;
typedef __attribute__((ext_vector_type(4))) float f32x4;

__device__ __forceinline__ unsigned short f2bf(float f) {
    unsigned int u = __float_as_uint(f);
    u += 0x7FFFu + ((u >> 16) & 1u);
    return (unsigned short)(u >> 16);
}

__device__ __forceinline__ void gld_lds16(const void* g, void* l) {
    __builtin_amdgcn_global_load_lds((const __attribute__((address_space(1))) void*)g,
                                     (__attribute__((address_space(3))) void*)l, 16, 0, 0);
}

// ---------------------------------------------------------------------------
// One wave per target t. Computes mean of 10 neighbor rows AND gathers x[tlid]
// row; writes BOTH into blocked bf16 A matrix:
//   Ag[rb][c][i][l][j]  (flat: rb*32768 + c*2048 + i*512 + l*8 + j)
// where row m = rb*64 + i*16 + (l&15), col k = c*32 + (l>>4)*8 + j.
// cols 0..255 = agg, 256..511 = x[tlid].
// ---------------------------------------------------------------------------
__global__ __launch_bounds__(256)
void agg_gather_kernel(const float* __restrict__ x, const int* __restrict__ src,
                       const int* __restrict__ tlid, unsigned short* __restrict__ Ag,
                       int T) {
    const int wave = threadIdx.x >> 6, lane = threadIdx.x & 63;
    const int t = blockIdx.x * 4 + wave;
    if (t >= T) return;
    const float4* x4 = (const float4*)x;
    const int* sp = src + (size_t)t * FANOUT;
    float sx = 0.f, sy = 0.f, sz = 0.f, sw = 0.f;
#pragma unroll
    for (int j = 0; j < FANOUT; ++j) {
        const float4 v = x4[(size_t)sp[j] * 64 + lane];
        sx += v.x; sy += v.y; sz += v.z; sw += v.w;
    }
    const float4 tv = x4[(size_t)tlid[t] * 64 + lane];

    // lane covers global cols 4*lane .. 4*lane+3 of each 256-wide half
    const int rb = t >> 6;
    const int i  = (t & 63) >> 4;
    const int m0 = t & 15;
    const int cl   = lane >> 3;          // chunk within half (0..7)
    const int quad = (lane >> 1) & 3;    // k-octet
    const int j0   = (lane & 1) * 4;     // 0 or 4 within octet
    const int lf   = quad * 16 + m0;     // fragment lane
    const size_t base = (size_t)rb * 32768 + (size_t)i * 512 + (size_t)lf * 8 + j0;

    ushort4 oa, ot;
    oa.x = f2bf(sx * 0.1f); oa.y = f2bf(sy * 0.1f);
    oa.z = f2bf(sz * 0.1f); oa.w = f2bf(sw * 0.1f);
    ot.x = f2bf(tv.x); ot.y = f2bf(tv.y); ot.z = f2bf(tv.z); ot.w = f2bf(tv.w);
    *(ushort4*)&Ag[base + (size_t)cl * 2048]       = oa;  // agg half   (c = cl)
    *(ushort4*)&Ag[base + (size_t)(cl + 8) * 2048] = ot;  // tlid half  (c = cl+8)
}

// ---------------------------------------------------------------------------
// Wt[c*8192 + n*32 + kc] = bf16( W'[c*32+kc][n] ), W' = [Wl; Wr] (K=512).
// ---------------------------------------------------------------------------
__global__ __launch_bounds__(256)
void convw_kernel(const float* __restrict__ Wl, const float* __restrict__ Wr,
                  unsigned short* __restrict__ Wt) {
    const int idx = blockIdx.x * 256 + threadIdx.x;   // 0 .. 131071
    const int kc = idx & 31, n = (idx >> 5) & 255, c = idx >> 13;
    const int k = c * 32 + kc;
    const float v = (k < 256) ? Wl[k * 256 + n] : Wr[(k - 256) * 256 + n];
    Wt[idx] = f2bf(v);
}

// ---------------------------------------------------------------------------
// h[rb*64 .. +64][0..256] = A[rb] @ W' + bias    (K = 512, bf16 MFMA)
// 256 threads = 4 waves; wave w owns cols [w*64, w*64+64); 4x4 16x16 tiles.
// ---------------------------------------------------------------------------
__global__ __launch_bounds__(256)
void gemm_mfma_kernel(const unsigned short* __restrict__ Ag,
                      const unsigned short* __restrict__ Wt,
                      const float* __restrict__ bias,
                      float* __restrict__ hbuf) {
    __shared__ unsigned short Alds[2048];   // 4 KB : [i][l][8]
    __shared__ unsigned short Blds[8192];   // 16 KB: [n][32]
    const int tid = threadIdx.x, wave = tid >> 6, lane = tid & 63;
    const size_t rb = blockIdx.x;

    f32x4 acc[4][4];
#pragma unroll
    for (int a = 0; a < 4; ++a)
#pragma unroll
        for (int b = 0; b < 4; ++b) acc[a][b] = (f32x4){0.f, 0.f, 0.f, 0.f};

    const unsigned short* Abase = Ag + rb * 32768;
    const int soff = wave * 512 + lane * 8;   // staging offset (ushorts)

    for (int c = 0; c < 16; ++c) {
        __syncthreads();
        gld_lds16(Abase + (size_t)c * 2048 + soff, &Alds[wave * 512]);
        const unsigned short* Bb = Wt + (size_t)c * 8192;
#pragma unroll
        for (int ii = 0; ii < 4; ++ii)
            gld_lds16(Bb + ii * 2048 + soff, &Blds[ii * 2048 + wave * 512]);
        __syncthreads();

        bf16x8 af[4], bfr[4];
#pragma unroll
        for (int mi = 0; mi < 4; ++mi)
            af[mi] = *(const bf16x8*)&Alds[(mi * 64 + lane) * 8];
        const int nb = wave * 64 + (lane & 15);
        const int ko = (lane >> 4) * 8;
#pragma unroll
        for (int t = 0; t < 4; ++t)
            bfr[t] = *(const bf16x8*)&Blds[(nb + t * 16) * 32 + ko];

#pragma unroll
        for (int mi = 0; mi < 4; ++mi)
#pragma unroll
            for (int t = 0; t < 4; ++t)
                acc[mi][t] = __builtin_amdgcn_mfma_f32_16x16x32_bf16(
                    af[mi], bfr[t], acc[mi][t], 0, 0, 0);
    }

    const int q = lane >> 4, m0 = lane & 15;
#pragma unroll
    for (int t = 0; t < 4; ++t) {
        const int col = wave * 64 + t * 16 + m0;
        const float bv = bias[col];
#pragma unroll
        for (int mi = 0; mi < 4; ++mi) {
            float* op = hbuf + (rb * 64 + (size_t)mi * 16 + q * 4) * 256 + col;
#pragma unroll
            for (int r = 0; r < 4; ++r)
                op[(size_t)r * 256] = acc[mi][t][r] + bv;
        }
    }
}

// ---------------------------------------------------------------------------
__global__ void zero_kernel(float* p) { p[threadIdx.x] = 0.f; }  // 512 threads

__global__ __launch_bounds__(256)
void stats_kernel(const float* __restrict__ h, float* __restrict__ ssum,
                  float* __restrict__ ssq, int T) {
    const int c = threadIdx.x;
    float s = 0.f, q = 0.f;
    for (int r = blockIdx.x; r < T; r += gridDim.x) {
        const float v = h[(size_t)r * HID + c];
        s += v;
        q += v * v;
    }
    atomicAdd(&ssum[c], s);
    atomicAdd(&ssq[c], q);
}

__global__ void bnfin_kernel(const float* __restrict__ ssum, const float* __restrict__ ssq,
                             const float* __restrict__ g, const float* __restrict__ be,
                             float* __restrict__ scal, float* __restrict__ shft,
                             float invT) {
    const int c = threadIdx.x;
    const float mu = ssum[c] * invT;
    float var = ssq[c] * invT - mu * mu;
    var = fmaxf(var, 0.f);
    const float rs = rsqrtf(var + 1e-5f);
    const float sc = rs * g[c];
    scal[c] = sc;
    shft[c] = be[c] - mu * sc;
}

__global__ __launch_bounds__(256)
void norm_kernel(float* __restrict__ h, const float* __restrict__ scal,
                 const float* __restrict__ shft, int n4) {
    const int i = blockIdx.x * blockDim.x + threadIdx.x;
    if (i >= n4) return;
    const int c4 = i & 63;
    float4 v = ((float4*)h)[i];
    const float4 sc = ((const float4*)scal)[c4];
    const float4 sh = ((const float4*)shft)[c4];
    v.x = fmaxf(fmaf(v.x, sc.x, sh.x), 0.f);
    v.y = fmaxf(fmaf(v.y, sc.y, sh.y), 0.f);
    v.z = fmaxf(fmaf(v.z, sc.z, sh.z), 0.f);
    v.w = fmaxf(fmaf(v.w, sc.w, sh.w), 0.f);
    ((float4*)h)[i] = v;
}

// ---------------------------------------------------------------------------
__global__ __launch_bounds__(64)
void fc_kernel(const float* __restrict__ x, const float* __restrict__ w,
               const float* __restrict__ b, float* __restrict__ out, int C) {
    __shared__ float row[HID];
    const int r = blockIdx.x;
    const int tid = threadIdx.x;
    ((float4*)row)[tid] = ((const float4*)(x + (size_t)r * HID))[tid];
    __syncthreads();
    if (tid < C) {
        float acc = b[tid];
#pragma unroll 8
        for (int k = 0; k < HID; ++k)
            acc = fmaf(row[k], w[k * C + tid], acc);
        out[(size_t)r * C + tid] = acc;
    }
}

// ---------------------------------------------------------------------------
extern "C" void kernel_launch(void* const* d_in, const int* in_sizes, int n_in,
                              void* d_out, int out_size, void* d_ws, size_t ws_size,
                              hipStream_t stream) {
    const float* x_feat = (const float*)d_in[0];
    const int T0 = in_sizes[3];   // 61952
    const int T1 = in_sizes[11];  // 5632
    const int T2 = in_sizes[19];  // 512
    const int NCLS = in_sizes[26];

    float* buf0 = (float*)d_ws;                  // h of layer 0 (fp32)
    float* buf1 = buf0 + (size_t)T0 * HID;
    float* buf2 = buf1 + (size_t)T1 * HID;
    float* ssum = buf2 + (size_t)T2 * HID;
    float* ssq  = ssum + HID;
    float* scal = ssq + HID;
    float* shft = scal + HID;
    unsigned short* Wt = (unsigned short*)(shft + HID + 256);   // 512*256 bf16
    unsigned short* Ag = Wt + 512 * 256;                        // T0*512 bf16 (reused)

    const float* xs[3]   = { x_feat, buf0, buf1 };
    float*       bufs[3] = { buf0, buf1, buf2 };
    const int    Ts[3]   = { T0, T1, T2 };

    for (int i = 0; i < 3; ++i) {
        const int base = 1 + i * 8;
        const int*   src  = (const int*)d_in[base + 0];
        const int*   tlid = (const int*)d_in[base + 2];
        const float* Wl   = (const float*)d_in[base + 3];
        const float* Wr   = (const float*)d_in[base + 4];
        const float* bi   = (const float*)d_in[base + 5];
        const float* g    = (const float*)d_in[base + 6];
        const float* be   = (const float*)d_in[base + 7];
        const int T = Ts[i];

        convw_kernel<<<512, 256, 0, stream>>>(Wl, Wr, Wt);
        agg_gather_kernel<<<(T + 3) / 4, 256, 0, stream>>>(xs[i], src, tlid, Ag, T);
        zero_kernel<<<1, 512, 0, stream>>>(ssum);
        gemm_mfma_kernel<<<T / 64, 256, 0, stream>>>(Ag, Wt, bi, bufs[i]);
        int sg = T / 64;
        if (sg > 256) sg = 256;
        if (sg < 1) sg = 1;
        stats_kernel<<<sg, 256, 0, stream>>>(bufs[i], ssum, ssq, T);
        bnfin_kernel<<<1, HID, 0, stream>>>(ssum, ssq, g, be, scal, shft, 1.0f / (float)T);
        norm_kernel<<<(T * 64 + 255) / 256, 256, 0, stream>>>(bufs[i], scal, shft, T * 64);
    }

    const float* fc_w = (const float*)d_in[25];
    const float* fc_b = (const float*)d_in[26];
    fc_kernel<<<T2, 64, 0, stream>>>(buf2, fc_w, fc_b, (float*)d_out, NCLS);
}

// Round 3
// 1062.841 us; speedup vs baseline: 1.4482x; 1.0842x over previous
//
#include <hip/hip_runtime.h>

#define HID 256
#define FANOUT 10

typedef __attribute__((ext_vector_type(8))) short bf16x8;
typedef __attribute__((ext_vector_type(4))) float f32x4;

__device__ __forceinline__ unsigned short f2bf(float f) {
    unsigned int u = __float_as_uint(f);
    u += 0x7FFFu + ((u >> 16) & 1u);
    return (unsigned short)(u >> 16);
}

__device__ __forceinline__ void gld_lds16(const void* g, void* l) {
    __builtin_amdgcn_global_load_lds((const __attribute__((address_space(1))) void*)g,
                                     (__attribute__((address_space(3))) void*)l, 16, 0, 0);
}

// ---------------------------------------------------------------------------
// One wave per target t. mean of 10 neighbor rows + x[tlid] gather, with the
// PREVIOUS layer's BN affine + ReLU applied on the fly (apply=1), written as
// blocked bf16 MFMA A-fragments:
//   Ag[rb][c][i][l][j]  (flat: rb*32768 + c*2048 + i*512 + l*8 + j)
//   row m = rb*64 + i*16 + (l&15), col k = c*32 + (l>>4)*8 + j.
// cols 0..255 = agg half, 256..511 = x[tlid] half.
// ---------------------------------------------------------------------------
__global__ __launch_bounds__(256)
void agg_gather_kernel(const float* __restrict__ x, const int* __restrict__ src,
                       const int* __restrict__ tlid, unsigned short* __restrict__ Ag,
                       int T, const float* __restrict__ scal,
                       const float* __restrict__ shft, int apply) {
    const int wave = threadIdx.x >> 6, lane = threadIdx.x & 63;
    const int t = blockIdx.x * 4 + wave;
    if (t >= T) return;
    const float4* x4 = (const float4*)x;
    float4 sc = make_float4(1.f, 1.f, 1.f, 1.f);
    float4 sh = make_float4(0.f, 0.f, 0.f, 0.f);
    if (apply) {
        sc = ((const float4*)scal)[lane];
        sh = ((const float4*)shft)[lane];
    }
    const int* sp = src + (size_t)t * FANOUT;
    float sx = 0.f, sy = 0.f, sz = 0.f, sw = 0.f;
#pragma unroll
    for (int j = 0; j < FANOUT; ++j) {
        float4 v = x4[(size_t)sp[j] * 64 + lane];
        if (apply) {
            v.x = fmaxf(fmaf(v.x, sc.x, sh.x), 0.f);
            v.y = fmaxf(fmaf(v.y, sc.y, sh.y), 0.f);
            v.z = fmaxf(fmaf(v.z, sc.z, sh.z), 0.f);
            v.w = fmaxf(fmaf(v.w, sc.w, sh.w), 0.f);
        }
        sx += v.x; sy += v.y; sz += v.z; sw += v.w;
    }
    float4 tv = x4[(size_t)tlid[t] * 64 + lane];
    if (apply) {
        tv.x = fmaxf(fmaf(tv.x, sc.x, sh.x), 0.f);
        tv.y = fmaxf(fmaf(tv.y, sc.y, sh.y), 0.f);
        tv.z = fmaxf(fmaf(tv.z, sc.z, sh.z), 0.f);
        tv.w = fmaxf(fmaf(tv.w, sc.w, sh.w), 0.f);
    }

    const int rb = t >> 6;
    const int i  = (t & 63) >> 4;
    const int m0 = t & 15;
    const int cl   = lane >> 3;
    const int quad = (lane >> 1) & 3;
    const int j0   = (lane & 1) * 4;
    const int lf   = quad * 16 + m0;
    const size_t base = (size_t)rb * 32768 + (size_t)i * 512 + (size_t)lf * 8 + j0;

    ushort4 oa, ot;
    oa.x = f2bf(sx * 0.1f); oa.y = f2bf(sy * 0.1f);
    oa.z = f2bf(sz * 0.1f); oa.w = f2bf(sw * 0.1f);
    ot.x = f2bf(tv.x); ot.y = f2bf(tv.y); ot.z = f2bf(tv.z); ot.w = f2bf(tv.w);
    *(ushort4*)&Ag[base + (size_t)cl * 2048]       = oa;
    *(ushort4*)&Ag[base + (size_t)(cl + 8) * 2048] = ot;
}

// ---------------------------------------------------------------------------
// All three layers' weights -> blocked bf16: Wt[L][c*8192 + n*32 + kc]
// ---------------------------------------------------------------------------
__global__ __launch_bounds__(256)
void convw_all_kernel(const float* __restrict__ Wl0, const float* __restrict__ Wr0,
                      const float* __restrict__ Wl1, const float* __restrict__ Wr1,
                      const float* __restrict__ Wl2, const float* __restrict__ Wr2,
                      unsigned short* __restrict__ Wt) {
    const int idx = blockIdx.x * 256 + threadIdx.x;     // 0 .. 393215
    const int layer = idx >> 17, r = idx & 131071;
    const float* Wl = (layer == 0) ? Wl0 : (layer == 1) ? Wl1 : Wl2;
    const float* Wr = (layer == 0) ? Wr0 : (layer == 1) ? Wr1 : Wr2;
    const int kc = r & 31, n = (r >> 5) & 255, c = r >> 13;
    const int k = c * 32 + kc;
    const float v = (k < 256) ? Wl[k * 256 + n] : Wr[(k - 256) * 256 + n];
    Wt[idx] = f2bf(v);
}

// ---------------------------------------------------------------------------
// h[rb*64..+64][0..256] = A[rb] @ W'  (K=512 bf16 MFMA, NO bias: BN cancels it)
// Epilogue: per-column partial sum/sumsq over the block's 64 rows ->
// shfl-reduce across q-groups -> one atomicAdd pair per column per block.
// ---------------------------------------------------------------------------
__global__ __launch_bounds__(256)
void gemm_mfma_kernel(const unsigned short* __restrict__ Ag,
                      const unsigned short* __restrict__ Wt,
                      float* __restrict__ hbuf,
                      float* __restrict__ ssum, float* __restrict__ ssq) {
    __shared__ unsigned short Alds[2048];   // 4 KB
    __shared__ unsigned short Blds[8192];   // 16 KB
    const int tid = threadIdx.x, wave = tid >> 6, lane = tid & 63;
    const size_t rb = blockIdx.x;

    f32x4 acc[4][4];
#pragma unroll
    for (int a = 0; a < 4; ++a)
#pragma unroll
        for (int b = 0; b < 4; ++b) acc[a][b] = (f32x4){0.f, 0.f, 0.f, 0.f};

    const unsigned short* Abase = Ag + rb * 32768;
    const int soff = wave * 512 + lane * 8;

    for (int c = 0; c < 16; ++c) {
        __syncthreads();
        gld_lds16(Abase + (size_t)c * 2048 + soff, &Alds[wave * 512]);
        const unsigned short* Bb = Wt + (size_t)c * 8192;
#pragma unroll
        for (int ii = 0; ii < 4; ++ii)
            gld_lds16(Bb + ii * 2048 + soff, &Blds[ii * 2048 + wave * 512]);
        __syncthreads();

        bf16x8 af[4], bfr[4];
#pragma unroll
        for (int mi = 0; mi < 4; ++mi)
            af[mi] = *(const bf16x8*)&Alds[(mi * 64 + lane) * 8];
        const int nb = wave * 64 + (lane & 15);
        const int ko = (lane >> 4) * 8;
#pragma unroll
        for (int t = 0; t < 4; ++t)
            bfr[t] = *(const bf16x8*)&Blds[(nb + t * 16) * 32 + ko];

#pragma unroll
        for (int mi = 0; mi < 4; ++mi)
#pragma unroll
            for (int t = 0; t < 4; ++t)
                acc[mi][t] = __builtin_amdgcn_mfma_f32_16x16x32_bf16(
                    af[mi], bfr[t], acc[mi][t], 0, 0, 0);
    }

    const int q = lane >> 4, m0 = lane & 15;

    // store h (no bias)
#pragma unroll
    for (int t = 0; t < 4; ++t) {
        const int col = wave * 64 + t * 16 + m0;
#pragma unroll
        for (int mi = 0; mi < 4; ++mi) {
            float* op = hbuf + (rb * 64 + (size_t)mi * 16 + q * 4) * 256 + col;
#pragma unroll
            for (int r = 0; r < 4; ++r)
                op[(size_t)r * 256] = acc[mi][t][r];
        }
    }

    // fused BN stats: per-thread partials over its 16 rows per column
    float s[4], sq[4];
#pragma unroll
    for (int t = 0; t < 4; ++t) {
        float a = 0.f, b = 0.f;
#pragma unroll
        for (int mi = 0; mi < 4; ++mi)
#pragma unroll
            for (int r = 0; r < 4; ++r) {
                const float v = acc[mi][t][r];
                a += v; b += v * v;
            }
        s[t] = a; sq[t] = b;
    }
#pragma unroll
    for (int t = 0; t < 4; ++t) {
        s[t] += __shfl_xor(s[t], 16);  s[t] += __shfl_xor(s[t], 32);
        sq[t] += __shfl_xor(sq[t], 16); sq[t] += __shfl_xor(sq[t], 32);
    }
    if (lane < 16) {
#pragma unroll
        for (int t = 0; t < 4; ++t) {
            const int col = wave * 64 + t * 16 + m0;
            atomicAdd(&ssum[col], s[t]);
            atomicAdd(&ssq[col], sq[t]);
        }
    }
}

// ---------------------------------------------------------------------------
__global__ void zero_kernel(float* p) { p[threadIdx.x] = 0.f; }  // 512 threads

__global__ void bnfin_kernel(const float* __restrict__ ssum, const float* __restrict__ ssq,
                             const float* __restrict__ g, const float* __restrict__ be,
                             float* __restrict__ scal, float* __restrict__ shft,
                             float invT) {
    const int c = threadIdx.x;
    const float mu = ssum[c] * invT;
    float var = ssq[c] * invT - mu * mu;
    var = fmaxf(var, 0.f);
    const float rs = rsqrtf(var + 1e-5f);
    const float sc = rs * g[c];
    scal[c] = sc;
    shft[c] = be[c] - mu * sc;
}

// ---------------------------------------------------------------------------
// out[r,n] = relu(bn(x3))[r,:] . fc_w[:,n] + fc_b[n]   (512 x 47)
// ---------------------------------------------------------------------------
__global__ __launch_bounds__(64)
void fc_kernel(const float* __restrict__ x, const float* __restrict__ scal,
               const float* __restrict__ shft, const float* __restrict__ w,
               const float* __restrict__ b, float* __restrict__ out, int C) {
    __shared__ float row[HID];
    const int r = blockIdx.x;
    const int tid = threadIdx.x;
    float4 v = ((const float4*)(x + (size_t)r * HID))[tid];
    const float4 sc = ((const float4*)scal)[tid];
    const float4 sh = ((const float4*)shft)[tid];
    v.x = fmaxf(fmaf(v.x, sc.x, sh.x), 0.f);
    v.y = fmaxf(fmaf(v.y, sc.y, sh.y), 0.f);
    v.z = fmaxf(fmaf(v.z, sc.z, sh.z), 0.f);
    v.w = fmaxf(fmaf(v.w, sc.w, sh.w), 0.f);
    ((float4*)row)[tid] = v;
    __syncthreads();
    if (tid < C) {
        float acc = b[tid];
#pragma unroll 8
        for (int k = 0; k < HID; ++k)
            acc = fmaf(row[k], w[k * C + tid], acc);
        out[(size_t)r * C + tid] = acc;
    }
}

// ---------------------------------------------------------------------------
extern "C" void kernel_launch(void* const* d_in, const int* in_sizes, int n_in,
                              void* d_out, int out_size, void* d_ws, size_t ws_size,
                              hipStream_t stream) {
    const float* x_feat = (const float*)d_in[0];
    const int T0 = in_sizes[3];   // 61952
    const int T1 = in_sizes[11];  // 5632
    const int T2 = in_sizes[19];  // 512
    const int NCLS = in_sizes[26];

    float* buf0 = (float*)d_ws;                  // h0 (pre-norm, fp32)
    float* buf1 = buf0 + (size_t)T0 * HID;
    float* buf2 = buf1 + (size_t)T1 * HID;
    float* ssum = buf2 + (size_t)T2 * HID;
    float* ssq  = ssum + HID;
    float* scal = ssq + HID;
    float* shft = scal + HID;
    unsigned short* Wt = (unsigned short*)(shft + HID + 256);   // 3 * 512*256 bf16
    unsigned short* Ag = Wt + 3 * 512 * 256;                    // T0*512 bf16 (reused)

    const float* xs[3]   = { x_feat, buf0, buf1 };
    float*       bufs[3] = { buf0, buf1, buf2 };
    const int    Ts[3]   = { T0, T1, T2 };

    convw_all_kernel<<<1536, 256, 0, stream>>>(
        (const float*)d_in[4],  (const float*)d_in[5],
        (const float*)d_in[12], (const float*)d_in[13],
        (const float*)d_in[20], (const float*)d_in[21], Wt);

    for (int i = 0; i < 3; ++i) {
        const int base = 1 + i * 8;
        const int*   src  = (const int*)d_in[base + 0];
        const int*   tlid = (const int*)d_in[base + 2];
        const float* g    = (const float*)d_in[base + 6];
        const float* be   = (const float*)d_in[base + 7];
        const int T = Ts[i];

        agg_gather_kernel<<<(T + 3) / 4, 256, 0, stream>>>(
            xs[i], src, tlid, Ag, T, scal, shft, i > 0 ? 1 : 0);
        zero_kernel<<<1, 512, 0, stream>>>(ssum);
        gemm_mfma_kernel<<<T / 64, 256, 0, stream>>>(
            Ag, Wt + (size_t)i * 131072, bufs[i], ssum, ssq);
        bnfin_kernel<<<1, HID, 0, stream>>>(ssum, ssq, g, be, scal, shft, 1.0f / (float)T);
    }

    const float* fc_w = (const float*)d_in[25];
    const float* fc_b = (const float*)d_in[26];
    fc_kernel<<<T2, 64, 0, stream>>>(buf2, scal, shft, fc_w, fc_b, (float*)d_out, NCLS);
}

// Round 4
// 1026.721 us; speedup vs baseline: 1.4991x; 1.0352x over previous
//
#include <hip/hip_runtime.h>

#define HID 256
#define FANOUT 10

typedef __attribute__((ext_vector_type(8))) short bf16x8;
typedef __attribute__((ext_vector_type(4))) float f32x4;

__device__ __forceinline__ unsigned short f2bf(float f) {
    unsigned int u = __float_as_uint(f);
    u += 0x7FFFu + ((u >> 16) & 1u);
    return (unsigned short)(u >> 16);
}

// ---------------------------------------------------------------------------
// All three layers' weights -> blocked bf16: Wt[L][c*8192 + n*32 + kc]
//   = bf16( W'[c*32+kc][n] ), W' = [Wl; Wr] (K = 512).
// ---------------------------------------------------------------------------
__global__ __launch_bounds__(256)
void convw_all_kernel(const float* __restrict__ Wl0, const float* __restrict__ Wr0,
                      const float* __restrict__ Wl1, const float* __restrict__ Wr1,
                      const float* __restrict__ Wl2, const float* __restrict__ Wr2,
                      unsigned short* __restrict__ Wt) {
    const int idx = blockIdx.x * 256 + threadIdx.x;     // 0 .. 393215
    const int layer = idx >> 17, r = idx & 131071;
    const float* Wl = (layer == 0) ? Wl0 : (layer == 1) ? Wl1 : Wl2;
    const float* Wr = (layer == 0) ? Wr0 : (layer == 1) ? Wr1 : Wr2;
    const int kc = r & 31, n = (r >> 5) & 255, c = r >> 13;
    const int k = c * 32 + kc;
    const float v = (k < 256) ? Wl[k * 256 + n] : Wr[(k - 256) * 256 + n];
    Wt[idx] = f2bf(v);
}

// ---------------------------------------------------------------------------
// Fused SAGE layer: block = 64 targets, 256 threads (4 waves).
// Phase 1: wave w gathers targets w*16..w*16+15 (10-nbr mean + tlid row),
//   applying previous layer's BN affine + ReLU on the fly (apply=1), and
//   writes bf16 MFMA A-fragments into LDS:
//     Alds[c*2048 + i*512 + lf*8 + j],  c = K-chunk (0..15), i = wave,
//     lf = quad*16 + m0 (fragment lane), m0 = target idx within wave.
// Phase 2 (one barrier, no LDS staging for W): K-loop, B-fragments loaded
//   straight from global Wt (contiguous 16 B per lane, L2-hot), MFMA.
// Epilogue: h store (fp32, no bias: BN cancels it) + fused BN stats
//   (shfl-reduce + one atomicAdd pair per column per block).
// ---------------------------------------------------------------------------
__global__ __launch_bounds__(256)
void fused_layer_kernel(const float* __restrict__ x, const int* __restrict__ src,
                        const int* __restrict__ tlid,
                        const unsigned short* __restrict__ Wt,
                        float* __restrict__ hbuf,
                        float* __restrict__ ssum, float* __restrict__ ssq,
                        const float* __restrict__ scal,
                        const float* __restrict__ shft, int apply) {
    __shared__ unsigned short Alds[32768];   // 64 KB
    const int tid = threadIdx.x, wave = tid >> 6, lane = tid & 63;
    const size_t rb = blockIdx.x;

    // ---- phase 1: gather + mean (+ BN/ReLU of previous layer) -> LDS frags
    const float4* x4 = (const float4*)x;
    float4 sc = make_float4(1.f, 1.f, 1.f, 1.f);
    float4 sh = make_float4(0.f, 0.f, 0.f, 0.f);
    if (apply) {
        sc = ((const float4*)scal)[lane];
        sh = ((const float4*)shft)[lane];
    }
    const int cl = lane >> 3;            // K-chunk within a 256-half (0..7)
    const int quad = (lane >> 1) & 3;    // k-octet
    const int j0 = (lane & 1) * 4;       // 0 or 4 within octet

    for (int ti = 0; ti < 16; ++ti) {
        const int t = (int)rb * 64 + wave * 16 + ti;
        const int* sp = src + (size_t)t * FANOUT;
        float sx = 0.f, sy = 0.f, sz = 0.f, sw = 0.f;
#pragma unroll
        for (int j = 0; j < FANOUT; ++j) {
            float4 v = x4[(size_t)sp[j] * 64 + lane];
            if (apply) {
                v.x = fmaxf(fmaf(v.x, sc.x, sh.x), 0.f);
                v.y = fmaxf(fmaf(v.y, sc.y, sh.y), 0.f);
                v.z = fmaxf(fmaf(v.z, sc.z, sh.z), 0.f);
                v.w = fmaxf(fmaf(v.w, sc.w, sh.w), 0.f);
            }
            sx += v.x; sy += v.y; sz += v.z; sw += v.w;
        }
        float4 tv = x4[(size_t)tlid[t] * 64 + lane];
        if (apply) {
            tv.x = fmaxf(fmaf(tv.x, sc.x, sh.x), 0.f);
            tv.y = fmaxf(fmaf(tv.y, sc.y, sh.y), 0.f);
            tv.z = fmaxf(fmaf(tv.z, sc.z, sh.z), 0.f);
            tv.w = fmaxf(fmaf(tv.w, sc.w, sh.w), 0.f);
        }
        ushort4 oa, ot;
        oa.x = f2bf(sx * 0.1f); oa.y = f2bf(sy * 0.1f);
        oa.z = f2bf(sz * 0.1f); oa.w = f2bf(sw * 0.1f);
        ot.x = f2bf(tv.x); ot.y = f2bf(tv.y); ot.z = f2bf(tv.z); ot.w = f2bf(tv.w);
        const int base = wave * 512 + (quad * 16 + ti) * 8 + j0;
        *(ushort4*)&Alds[cl * 2048 + base]       = oa;   // agg half  (chunks 0..7)
        *(ushort4*)&Alds[(cl + 8) * 2048 + base] = ot;   // tlid half (chunks 8..15)
    }
    __syncthreads();

    // ---- phase 2: K-loop, barrier-free
    f32x4 acc[4][4];
#pragma unroll
    for (int a = 0; a < 4; ++a)
#pragma unroll
        for (int b = 0; b < 4; ++b) acc[a][b] = (f32x4){0.f, 0.f, 0.f, 0.f};

    const int nb = wave * 64 + (lane & 15);
    const int ko = (lane >> 4) * 8;
#pragma unroll
    for (int c = 0; c < 16; ++c) {
        bf16x8 af[4], bfr[4];
#pragma unroll
        for (int mi = 0; mi < 4; ++mi)
            af[mi] = *(const bf16x8*)&Alds[c * 2048 + mi * 512 + lane * 8];
#pragma unroll
        for (int t = 0; t < 4; ++t)
            bfr[t] = *(const bf16x8*)&Wt[(size_t)c * 8192 + (nb + t * 16) * 32 + ko];
#pragma unroll
        for (int mi = 0; mi < 4; ++mi)
#pragma unroll
            for (int t = 0; t < 4; ++t)
                acc[mi][t] = __builtin_amdgcn_mfma_f32_16x16x32_bf16(
                    af[mi], bfr[t], acc[mi][t], 0, 0, 0);
    }

    // ---- epilogue: store h + fused BN stats
    const int q = lane >> 4, m0 = lane & 15;
#pragma unroll
    for (int t = 0; t < 4; ++t) {
        const int col = wave * 64 + t * 16 + m0;
#pragma unroll
        for (int mi = 0; mi < 4; ++mi) {
            float* op = hbuf + (rb * 64 + (size_t)mi * 16 + q * 4) * 256 + col;
#pragma unroll
            for (int r = 0; r < 4; ++r)
                op[(size_t)r * 256] = acc[mi][t][r];
        }
    }

    float s[4], sq[4];
#pragma unroll
    for (int t = 0; t < 4; ++t) {
        float a = 0.f, b = 0.f;
#pragma unroll
        for (int mi = 0; mi < 4; ++mi)
#pragma unroll
            for (int r = 0; r < 4; ++r) {
                const float v = acc[mi][t][r];
                a += v; b += v * v;
            }
        s[t] = a; sq[t] = b;
    }
#pragma unroll
    for (int t = 0; t < 4; ++t) {
        s[t] += __shfl_xor(s[t], 16);  s[t] += __shfl_xor(s[t], 32);
        sq[t] += __shfl_xor(sq[t], 16); sq[t] += __shfl_xor(sq[t], 32);
    }
    if (lane < 16) {
#pragma unroll
        for (int t = 0; t < 4; ++t) {
            const int col = wave * 64 + t * 16 + m0;
            atomicAdd(&ssum[col], s[t]);
            atomicAdd(&ssq[col], sq[t]);
        }
    }
}

// ---------------------------------------------------------------------------
__global__ void zero_kernel(float* p) { p[threadIdx.x] = 0.f; }  // 512 threads

__global__ void bnfin_kernel(const float* __restrict__ ssum, const float* __restrict__ ssq,
                             const float* __restrict__ g, const float* __restrict__ be,
                             float* __restrict__ scal, float* __restrict__ shft,
                             float invT) {
    const int c = threadIdx.x;
    const float mu = ssum[c] * invT;
    float var = ssq[c] * invT - mu * mu;
    var = fmaxf(var, 0.f);
    const float rs = rsqrtf(var + 1e-5f);
    const float sc = rs * g[c];
    scal[c] = sc;
    shft[c] = be[c] - mu * sc;
}

// ---------------------------------------------------------------------------
// out[r,n] = relu(bn(x3))[r,:] . fc_w[:,n] + fc_b[n]   (512 x 47)
// ---------------------------------------------------------------------------
__global__ __launch_bounds__(64)
void fc_kernel(const float* __restrict__ x, const float* __restrict__ scal,
               const float* __restrict__ shft, const float* __restrict__ w,
               const float* __restrict__ b, float* __restrict__ out, int C) {
    __shared__ float row[HID];
    const int r = blockIdx.x;
    const int tid = threadIdx.x;
    float4 v = ((const float4*)(x + (size_t)r * HID))[tid];
    const float4 sc = ((const float4*)scal)[tid];
    const float4 sh = ((const float4*)shft)[tid];
    v.x = fmaxf(fmaf(v.x, sc.x, sh.x), 0.f);
    v.y = fmaxf(fmaf(v.y, sc.y, sh.y), 0.f);
    v.z = fmaxf(fmaf(v.z, sc.z, sh.z), 0.f);
    v.w = fmaxf(fmaf(v.w, sc.w, sh.w), 0.f);
    ((float4*)row)[tid] = v;
    __syncthreads();
    if (tid < C) {
        float acc = b[tid];
#pragma unroll 8
        for (int k = 0; k < HID; ++k)
            acc = fmaf(row[k], w[k * C + tid], acc);
        out[(size_t)r * C + tid] = acc;
    }
}

// ---------------------------------------------------------------------------
extern "C" void kernel_launch(void* const* d_in, const int* in_sizes, int n_in,
                              void* d_out, int out_size, void* d_ws, size_t ws_size,
                              hipStream_t stream) {
    const float* x_feat = (const float*)d_in[0];
    const int T0 = in_sizes[3];   // 61952
    const int T1 = in_sizes[11];  // 5632
    const int T2 = in_sizes[19];  // 512
    const int NCLS = in_sizes[26];

    float* buf0 = (float*)d_ws;                  // h0 (pre-norm, fp32)
    float* buf1 = buf0 + (size_t)T0 * HID;
    float* buf2 = buf1 + (size_t)T1 * HID;
    float* ssum = buf2 + (size_t)T2 * HID;
    float* ssq  = ssum + HID;
    float* scal = ssq + HID;
    float* shft = scal + HID;
    unsigned short* Wt = (unsigned short*)(shft + HID + 256);   // 3 * 512*256 bf16

    const float* xs[3]   = { x_feat, buf0, buf1 };
    float*       bufs[3] = { buf0, buf1, buf2 };
    const int    Ts[3]   = { T0, T1, T2 };

    convw_all_kernel<<<1536, 256, 0, stream>>>(
        (const float*)d_in[4],  (const float*)d_in[5],
        (const float*)d_in[12], (const float*)d_in[13],
        (const float*)d_in[20], (const float*)d_in[21], Wt);

    for (int i = 0; i < 3; ++i) {
        const int base = 1 + i * 8;
        const int*   src  = (const int*)d_in[base + 0];
        const int*   tlid = (const int*)d_in[base + 2];
        const float* g    = (const float*)d_in[base + 6];
        const float* be   = (const float*)d_in[base + 7];
        const int T = Ts[i];

        zero_kernel<<<1, 512, 0, stream>>>(ssum);
        fused_layer_kernel<<<T / 64, 256, 0, stream>>>(
            xs[i], src, tlid, Wt + (size_t)i * 131072, bufs[i],
            ssum, ssq, scal, shft, i > 0 ? 1 : 0);
        bnfin_kernel<<<1, HID, 0, stream>>>(ssum, ssq, g, be, scal, shft, 1.0f / (float)T);
    }

    const float* fc_w = (const float*)d_in[25];
    const float* fc_b = (const float*)d_in[26];
    fc_kernel<<<T2, 64, 0, stream>>>(buf2, scal, shft, fc_w, fc_b, (float*)d_out, NCLS);
}